// Round 3
// baseline (49211.771 us; speedup 1.0000x reference)
//
#include <hip/hip_runtime.h>

typedef unsigned short u16;
typedef unsigned int u32;
typedef unsigned long long u64;
typedef __attribute__((ext_vector_type(8))) short bf16x8;   // 8 bf16 (4 VGPRs)
typedef __attribute__((ext_vector_type(4))) float f32x4;

#define T_STEPS 1024
#define E_SZ 128
#define U_SZ 256

#define NG 16   // batch groups
#define NS 16   // unit slices (wgs per group)
#define MB 16   // batch rows per group (MFMA M)
#define HS 264  // padded LDS row stride for K=256 (bank-conflict pad, 16B-mult)
#define EPAD 136 // padded LDS row stride for K=128

// LDS byte offsets (all 16B aligned)
#define OFF_W0T 0                    // 64*EPAD*2 = 17408
#define OFF_R0T 17408                // 64*HS*2   = 33792
#define OFF_W1T 51200                // 33792
#define OFF_R1T 84992                // 33792
#define OFF_H0  118784               // 16*HS*2   = 8448
#define OFF_H1  127232               // 8448
#define OFF_X   135680               // 16*EPAD*2 = 4352
#define OFF_G   140032               // 4*16*17*4 = 4352 (gate scratch, also epilogue scratch)
#define OFF_STG 144384               // 16*16*2   = 512
#define OFF_B0  144896               // 64*4
#define OFF_B1  145152               // 64*4
#define SMEM_TOTAL 145408            // ~142 KiB <= 160 KiB

// Exchange state in module globals (size-safe); counters zeroed by probe kernel.
__device__ u64 g_exch0[2 * NG * MB * 64];   // 256 KiB, [parity][g][m][u/4]
__device__ u64 g_exch1[2 * NG * MB * 64];   // 256 KiB
__device__ int g_cnt[64];                   // 2 monotonic counters per group
__device__ int g_isF32;                     // dtype flag set by probe

__device__ __forceinline__ float bf2f(u16 u) {
  union { u32 i; float f; } v; v.i = ((u32)u) << 16; return v.f;
}
__device__ __forceinline__ u16 f2bf(float f) {
  union { u32 i; float f; } v; v.f = f;
  u32 r = v.i + 0x7fffu + ((v.i >> 16) & 1u);  // round-nearest-even
  return (u16)(r >> 16);
}
__device__ __forceinline__ float sigmoidf_(float x) { return 1.f / (1.f + __expf(-x)); }

// ---- dtype probe: f32 data read as u16 has ~25% "huge bf16" halves; real bf16
// weights (sigma~0.09) have none. Also zeroes the sync counters each call. ----
extern "C" __global__ void dtype_probe(const void* W0v) {
  __shared__ int cntBig;
  if (threadIdx.x == 0) cntBig = 0;
  __syncthreads();
  const u16* u = (const u16*)W0v;
  int big = 0;
  for (int i = threadIdx.x; i < 4096; i += 256)
    if ((u[i] & 0x7F80u) >= 0x4100u) big++;   // |decode| >= 8
  atomicAdd(&cntBig, big);
  __syncthreads();
  if (threadIdx.x < 64) g_cnt[threadIdx.x] = 0;
  if (threadIdx.x == 0) g_isF32 = (cntBig > 100) ? 1 : 0;
}

// ---- inter-workgroup exchange helpers (agent scope => correct across XCDs) ----

__device__ __forceinline__ void postSlice(u64* __restrict__ exch, int t, int g, int s,
                                          int tid, const u16* __restrict__ stg,
                                          int* __restrict__ cntp) {
  const int p = t & 1;
  const u64 base = (u64)((p * NG + g) * MB) * 64;   // u64 units: [p][g][m][u/4]
  if (tid < 64) {
    int m = tid >> 2, j = tid & 3;                  // 4 u64 per batch row
    u64 v = *(const u64*)(stg + (m << 4) + (j << 2));
    __hip_atomic_store(exch + base + m * 64 + (s << 2) + j, v,
                       __ATOMIC_RELAXED, __HIP_MEMORY_SCOPE_AGENT);
  }
  __threadfence();        // agent fence: slice stores visible before arrival
  __syncthreads();
  if (tid == 0)
    __hip_atomic_fetch_add(cntp, 1, __ATOMIC_RELEASE, __HIP_MEMORY_SCOPE_AGENT);
}

__device__ __forceinline__ void waitCnt(int* __restrict__ cntp, int target, int tid,
                                        int* abortF) {
  if (tid == 0 && !(*abortF)) {
    int cap = 20000000;   // safety: convert deadlock into fast wrong-answer, not a hang
    while (__hip_atomic_load(cntp, __ATOMIC_ACQUIRE, __HIP_MEMORY_SCOPE_AGENT) < target) {
      __builtin_amdgcn_s_sleep(2);
      if (--cap <= 0) { *abortF = 1; break; }
    }
  }
  __syncthreads();
}

__device__ __forceinline__ void readback(const u64* __restrict__ exch, int t, int g,
                                         int tid, u16* __restrict__ ldsH) {
  const int p = t & 1;
  const u64 base = (u64)((p * NG + g) * MB) * 64;
  const int m = tid >> 4;
  const int r = (tid & 15) << 2;
#pragma unroll
  for (int j = 0; j < 4; j++) {
    u64 v = __hip_atomic_load(exch + base + m * 64 + r + j,
                              __ATOMIC_RELAXED, __HIP_MEMORY_SCOPE_AGENT);
    *(u64*)(ldsH + m * HS + ((r + j) << 2)) = v;
  }
  __syncthreads();
}

extern "C" __global__ void __launch_bounds__(256)
lstm_fused(const int* __restrict__ tokens, const void* __restrict__ emb,
           const void* __restrict__ W0, const void* __restrict__ R0, const void* __restrict__ b0,
           const void* __restrict__ W1, const void* __restrict__ R1, const void* __restrict__ b1,
           const void* __restrict__ Wout, const void* __restrict__ bout,
           void* __restrict__ outv) {
  extern __shared__ char smem[];
  u16* w0t   = (u16*)(smem + OFF_W0T);
  u16* r0t   = (u16*)(smem + OFF_R0T);
  u16* w1t   = (u16*)(smem + OFF_W1T);
  u16* r1t   = (u16*)(smem + OFF_R1T);
  u16* ldsH0 = (u16*)(smem + OFF_H0);
  u16* ldsH1 = (u16*)(smem + OFF_H1);
  u16* ldsX  = (u16*)(smem + OFF_X);
  float* ldsG = (float*)(smem + OFF_G);
  u16* stg   = (u16*)(smem + OFF_STG);
  float* ldsB0 = (float*)(smem + OFF_B0);
  float* ldsB1 = (float*)(smem + OFF_B1);
  __shared__ int abortF;

  const int tid = threadIdx.x;
  const int g = blockIdx.x & (NG - 1);   // group
  const int s = blockIdx.x >> 4;         // unit slice
  const int isF32 = g_isF32;             // wave-uniform dtype flag (probe ran first)

  if (tid == 0) abortF = 0;

  // generic float load: f32 direct or bf16 decode
  auto ldf = [&](const void* p, int idx) -> float {
    return isF32 ? ((const float*)p)[idx] : bf2f(((const u16*)p)[idx]);
  };

  // ---- one-time: load transposed weight slices into LDS (as bf16) ----
  // slice cols: gate q in {i,f,g,o}: global col = q*256 + s*16 + nn; LDS row n = q*16+nn
  for (int i = tid; i < 64 * E_SZ; i += 256) {
    int k = i >> 6, n = i & 63;
    int col = ((n >> 4) << 8) + (s << 4) + (n & 15);
    w0t[n * EPAD + k] = f2bf(ldf(W0, k * 1024 + col));
  }
  for (int i = tid; i < 64 * U_SZ; i += 256) {
    int k = i >> 6, n = i & 63;
    int col = ((n >> 4) << 8) + (s << 4) + (n & 15);
    r0t[n * HS + k] = f2bf(ldf(R0, k * 1024 + col));
    w1t[n * HS + k] = f2bf(ldf(W1, k * 1024 + col));
    r1t[n * HS + k] = f2bf(ldf(R1, k * 1024 + col));
  }
  if (tid < 64) {
    int col = ((tid >> 4) << 8) + (s << 4) + (tid & 15);
    ldsB0[tid] = ldf(b0, col);
    ldsB1[tid] = ldf(b1, col);
  }
  for (int i = tid; i < MB * U_SZ; i += 256) {   // h0 = h1 = 0
    int m = i >> 8, k = i & 255;
    ldsH0[m * HS + k] = 0;
    ldsH1[m * HS + k] = 0;
  }
  __syncthreads();

  const int lane = tid & 63;
  const int wv = tid >> 6;       // wave id == gate q (i,f,g,o)
  const int ml = lane & 15;      // A row / B-D col within tile
  const int quad = lane >> 4;
  const int um = tid >> 4;       // update phase: batch row
  const int un = tid & 15;       // update phase: unit within slice

  float c0 = 0.f, c1 = 0.f;      // f32 cell state in registers (tid->(m,u) fixed)
  int* cnt0 = g_cnt + g * 2;
  int* cnt1 = g_cnt + g * 2 + 1;

  for (int t = 0; t < T_STEPS; t++) {
    // 1. gather x_t rows for this group's 16 batches -> bf16 in LDS
    {
      int tok = tokens[(g * MB + um) * T_STEPS + t];
      if (isF32) {
        const float* row = (const float*)emb + (u64)tok * E_SZ + (un << 3);
        float4 a = *(const float4*)row;
        float4 bq = *(const float4*)(row + 4);
        uint4 pk;
        pk.x = (u32)f2bf(a.x)  | ((u32)f2bf(a.y)  << 16);
        pk.y = (u32)f2bf(a.z)  | ((u32)f2bf(a.w)  << 16);
        pk.z = (u32)f2bf(bq.x) | ((u32)f2bf(bq.y) << 16);
        pk.w = (u32)f2bf(bq.z) | ((u32)f2bf(bq.w) << 16);
        *(uint4*)(ldsX + um * EPAD + (un << 3)) = pk;
      } else {
        *(uint4*)(ldsX + um * EPAD + (un << 3)) =
            *(const uint4*)((const u16*)emb + (u64)tok * E_SZ + (un << 3));
      }
    }
    __syncthreads();

    // 2. z0 slice = x@W0s + h0_{t-1}@R0s + b0s   (wave wv owns gate wv, 16 cols)
    {
      float bias = ldsB0[(wv << 4) + ml];
      f32x4 acc = {bias, bias, bias, bias};
      const u16* ar = ldsX + ml * EPAD + (quad << 3);
      const u16* br = w0t + ((wv << 4) + ml) * EPAD + (quad << 3);
#pragma unroll
      for (int kc = 0; kc < 4; kc++) {
        bf16x8 av = *(const bf16x8*)(ar + kc * 32);
        bf16x8 bv = *(const bf16x8*)(br + kc * 32);
        acc = __builtin_amdgcn_mfma_f32_16x16x32_bf16(av, bv, acc, 0, 0, 0);
      }
      const u16* ar2 = ldsH0 + ml * HS + (quad << 3);
      const u16* br2 = r0t + ((wv << 4) + ml) * HS + (quad << 3);
#pragma unroll
      for (int kc = 0; kc < 8; kc++) {
        bf16x8 av = *(const bf16x8*)(ar2 + kc * 32);
        bf16x8 bv = *(const bf16x8*)(br2 + kc * 32);
        acc = __builtin_amdgcn_mfma_f32_16x16x32_bf16(av, bv, acc, 0, 0, 0);
      }
#pragma unroll
      for (int r = 0; r < 4; r++) {   // C/D: col=lane&15, row=quad*4+r
        float v = acc[r];
        float gv = (wv == 2) ? tanhf(v) : sigmoidf_(v);   // gate order i,f,g,o
        ldsG[((wv << 4) + (quad << 2) + r) * 17 + ml] = gv;
      }
    }
    __syncthreads();

    // 3. cell update layer 0
    {
      float iv = ldsG[um * 17 + un];
      float fv = ldsG[(16 + um) * 17 + un];
      float gv = ldsG[(32 + um) * 17 + un];
      float ov = ldsG[(48 + um) * 17 + un];
      c0 = fv * c0 + iv * gv;
      float h = ov * tanhf(c0);
      stg[(um << 4) + un] = f2bf(h);
    }
    __syncthreads();

    // 4. publish h0_t slice; deferred wait on h1_{t-1}; wait h0_t
    postSlice(g_exch0, t, g, s, tid, stg, cnt0);
    if (t > 0) {
      waitCnt(cnt1, NS * t, tid, &abortF);
      readback(g_exch1, t - 1, g, tid, ldsH1);
    }
    waitCnt(cnt0, NS * (t + 1), tid, &abortF);
    readback(g_exch0, t, g, tid, ldsH0);

    // 5. z1 slice = h0_t@W1s + h1_{t-1}@R1s + b1s
    {
      float bias = ldsB1[(wv << 4) + ml];
      f32x4 acc = {bias, bias, bias, bias};
      const u16* ar = ldsH0 + ml * HS + (quad << 3);
      const u16* br = w1t + ((wv << 4) + ml) * HS + (quad << 3);
#pragma unroll
      for (int kc = 0; kc < 8; kc++) {
        bf16x8 av = *(const bf16x8*)(ar + kc * 32);
        bf16x8 bv = *(const bf16x8*)(br + kc * 32);
        acc = __builtin_amdgcn_mfma_f32_16x16x32_bf16(av, bv, acc, 0, 0, 0);
      }
      const u16* ar2 = ldsH1 + ml * HS + (quad << 3);
      const u16* br2 = r1t + ((wv << 4) + ml) * HS + (quad << 3);
#pragma unroll
      for (int kc = 0; kc < 8; kc++) {
        bf16x8 av = *(const bf16x8*)(ar2 + kc * 32);
        bf16x8 bv = *(const bf16x8*)(br2 + kc * 32);
        acc = __builtin_amdgcn_mfma_f32_16x16x32_bf16(av, bv, acc, 0, 0, 0);
      }
#pragma unroll
      for (int r = 0; r < 4; r++) {
        float v = acc[r];
        float gv = (wv == 2) ? tanhf(v) : sigmoidf_(v);
        ldsG[((wv << 4) + (quad << 2) + r) * 17 + ml] = gv;
      }
    }
    __syncthreads();

    // 6. cell update layer 1
    {
      float iv = ldsG[um * 17 + un];
      float fv = ldsG[(16 + um) * 17 + un];
      float gv = ldsG[(32 + um) * 17 + un];
      float ov = ldsG[(48 + um) * 17 + un];
      c1 = fv * c1 + iv * gv;
      float h = ov * tanhf(c1);
      stg[(um << 4) + un] = f2bf(h);
    }
    __syncthreads();

    // 7. publish h1_t slice; NO wait here (consumed next iteration)
    postSlice(g_exch1, t, g, s, tid, stg, cnt1);
  }

  // ---- epilogue: logits = h1_final @ Wout + bout; sigmoid ----
  if (s == 0) {
    waitCnt(cnt1, NS * T_STEPS, tid, &abortF);
    readback(g_exch1, T_STEPS - 1, g, tid, ldsH1);
    float* woutf = ldsG;          // 256 floats
    float* red = ldsG + 272;      // 16x17 partials
    woutf[tid] = ldf(Wout, tid);
    __syncthreads();
    float p = 0.f;
#pragma unroll
    for (int j = 0; j < 16; j++)
      p += bf2f(ldsH1[um * HS + (un << 4) + j]) * woutf[(un << 4) + j];
    red[um * 17 + un] = p;
    __syncthreads();
    if (tid < 16) {
      float sum = ldf(bout, 0);
#pragma unroll
      for (int j = 0; j < 16; j++) sum += red[tid * 17 + j];
      float val = sigmoidf_(sum);
      if (isF32) ((float*)outv)[g * MB + tid] = val;
      else       ((u16*)outv)[g * MB + tid] = f2bf(val);
    }
  }
}

extern "C" void kernel_launch(void* const* d_in, const int* in_sizes, int n_in,
                              void* d_out, int out_size, void* d_ws, size_t ws_size,
                              hipStream_t stream) {
  const int* tokens = (const int*)d_in[0];
  const void* emb  = d_in[1];
  const void* W0   = d_in[2];
  const void* R0   = d_in[3];
  const void* b0   = d_in[4];
  const void* W1   = d_in[5];
  const void* R1   = d_in[6];
  const void* b1   = d_in[7];
  const void* Wout = d_in[8];
  const void* bout = d_in[9];

  hipFuncSetAttribute((const void*)lstm_fused,
                      hipFuncAttributeMaxDynamicSharedMemorySize, SMEM_TOTAL);

  // probe: detects f32-vs-bf16 storage, zeroes sync counters (stream-ordered)
  dtype_probe<<<dim3(1), dim3(256), 0, stream>>>(W0);

  // grid = 256 wgs, 142 KiB LDS each -> exactly 1 wg/CU on 256 CUs: co-resident.
  lstm_fused<<<dim3(256), dim3(256), SMEM_TOTAL, stream>>>(
      tokens, emb, W0, R0, b0, W1, R1, b1, Wout, bout, d_out);
}

// Round 4
// 24420.872 us; speedup vs baseline: 2.0152x; 2.0152x over previous
//
#include <hip/hip_runtime.h>

typedef unsigned short u16;
typedef unsigned int u32;
typedef unsigned long long u64;
typedef __attribute__((ext_vector_type(8))) short bf16x8;   // 8 bf16 (4 VGPRs)
typedef __attribute__((ext_vector_type(4))) float f32x4;

#define T_STEPS 1024
#define E_SZ 128
#define U_SZ 256

#define NG 16   // batch groups
#define NS 16   // unit slices (wgs per group)
#define MB 16   // batch rows per group (MFMA M)
#define HS 264  // padded LDS row stride for K=256
#define EPAD 136 // padded LDS row stride for K=128

// LDS byte offsets (all 16B aligned)
#define OFF_W0T 0                    // 64*EPAD*2 = 17408
#define OFF_R0T 17408                // 64*HS*2   = 33792
#define OFF_W1T 51200                // 33792
#define OFF_R1T 84992                // 33792
#define OFF_H0  118784               // 16*HS*2   = 8448
#define OFF_H1  127232               // 8448
#define OFF_X   135680               // 16*EPAD*2 = 4352
#define OFF_G   140032               // 4*16*17*4 = 4352
#define OFF_STG 144384               // 16*16*2   = 512
#define OFF_B0  144896               // 64*4
#define OFF_B1  145152               // 64*4
#define SMEM_TOTAL 145408            // ~142 KiB <= 160 KiB

// Exchange state in module globals. Flags: one 256B row per group (64 ints),
// slice s's flag at [g*64+s] -> no RMW, no cross-group false sharing.
__device__ u64 g_exch0[2 * NG * MB * 64];   // 256 KiB, [parity][g][m][u/4]
__device__ u64 g_exch1[2 * NG * MB * 64];   // 256 KiB
__device__ int g_flags0[NG * 64];
__device__ int g_flags1[NG * 64];
__device__ int g_isF32;                     // dtype flag set by probe

__device__ __forceinline__ float bf2f(u16 u) {
  union { u32 i; float f; } v; v.i = ((u32)u) << 16; return v.f;
}
__device__ __forceinline__ u16 f2bf(float f) {
  union { u32 i; float f; } v; v.f = f;
  u32 r = v.i + 0x7fffu + ((v.i >> 16) & 1u);  // round-nearest-even
  return (u16)(r >> 16);
}
__device__ __forceinline__ float sigmoidf_(float x) { return 1.f / (1.f + __expf(-x)); }

// ---- dtype probe: f32 data read as u16 has ~25% "huge bf16" halves; real bf16
// weights (sigma~0.09) have none. Also zeroes the sync flags each call. ----
extern "C" __global__ void dtype_probe(const void* W0v) {
  __shared__ int cntBig;
  if (threadIdx.x == 0) cntBig = 0;
  __syncthreads();
  const u16* u = (const u16*)W0v;
  int big = 0;
  for (int i = threadIdx.x; i < 4096; i += 256)
    if ((u[i] & 0x7F80u) >= 0x4100u) big++;   // |decode| >= 8
  atomicAdd(&cntBig, big);
  __syncthreads();
  for (int i = threadIdx.x; i < NG * 64; i += 256) { g_flags0[i] = 0; g_flags1[i] = 0; }
  if (threadIdx.x == 0) g_isF32 = (cntBig > 100) ? 1 : 0;
}

// ---- inter-workgroup exchange (agent scope => correct across XCDs) ----
// post: wave-0 only. 64 relaxed 8B data stores -> wave-level release fence
// (drains the wave's stores) -> single relaxed flag store. No RMW, no barrier.
__device__ __forceinline__ void postSlice(u64* __restrict__ exch, int* __restrict__ flags,
                                          int t, int g, int s, int tid,
                                          const u16* __restrict__ stg) {
  const int p = t & 1;
  const u64 base = (u64)((p * NG + g) * MB) * 64;   // u64 units: [p][g][m][u/4]
  if (tid < 64) {
    int m = tid >> 2, j = tid & 3;                  // 4 u64 per batch row
    u64 v = *(const u64*)(stg + (m << 4) + (j << 2));
    __hip_atomic_store(exch + base + m * 64 + (s << 2) + j, v,
                       __ATOMIC_RELAXED, __HIP_MEMORY_SCOPE_AGENT);
    __builtin_amdgcn_fence(__ATOMIC_RELEASE, "agent");
    if (tid == 0)
      __hip_atomic_store(flags + g * 64 + s, t + 1,
                         __ATOMIC_RELAXED, __HIP_MEMORY_SCOPE_AGENT);
  }
}

// wait: 16 lanes poll their own flag word RELAXED (no per-poll invalidates),
// then one acquire fence for the whole block.
__device__ __forceinline__ void waitFlags(int* __restrict__ flags, int g, int target,
                                          int tid, int* abortF) {
  if (tid < 16 && !(*abortF)) {
    int cap = 2000000;   // safety: convert deadlock into fast wrong-answer, not a hang
    while (__hip_atomic_load(flags + g * 64 + tid,
                             __ATOMIC_RELAXED, __HIP_MEMORY_SCOPE_AGENT) < target) {
      __builtin_amdgcn_s_sleep(1);
      if (--cap <= 0) { *abortF = 1; break; }
    }
  }
  __syncthreads();
  __builtin_amdgcn_fence(__ATOMIC_ACQUIRE, "agent");
}

__device__ __forceinline__ void readback(const u64* __restrict__ exch, int t, int g,
                                         int tid, u16* __restrict__ ldsH) {
  const int p = t & 1;
  const u64 base = (u64)((p * NG + g) * MB) * 64;
  const int m = tid >> 4;
  const int r = (tid & 15) << 2;
#pragma unroll
  for (int j = 0; j < 4; j++) {
    u64 v = __hip_atomic_load(exch + base + m * 64 + r + j,
                              __ATOMIC_RELAXED, __HIP_MEMORY_SCOPE_AGENT);
    *(u64*)(ldsH + m * HS + ((r + j) << 2)) = v;
  }
  __syncthreads();
}

extern "C" __global__ void __launch_bounds__(256)
lstm_fused(const int* __restrict__ tokens, const void* __restrict__ emb,
           const void* __restrict__ W0, const void* __restrict__ R0, const void* __restrict__ b0,
           const void* __restrict__ W1, const void* __restrict__ R1, const void* __restrict__ b1,
           const void* __restrict__ Wout, const void* __restrict__ bout,
           void* __restrict__ outv) {
  extern __shared__ char smem[];
  u16* w0t   = (u16*)(smem + OFF_W0T);
  u16* r0t   = (u16*)(smem + OFF_R0T);
  u16* w1t   = (u16*)(smem + OFF_W1T);
  u16* r1t   = (u16*)(smem + OFF_R1T);
  u16* ldsH0 = (u16*)(smem + OFF_H0);
  u16* ldsH1 = (u16*)(smem + OFF_H1);
  u16* ldsX  = (u16*)(smem + OFF_X);
  float* ldsG = (float*)(smem + OFF_G);
  u16* stg   = (u16*)(smem + OFF_STG);
  float* ldsB0 = (float*)(smem + OFF_B0);
  float* ldsB1 = (float*)(smem + OFF_B1);
  __shared__ int abortF;

  const int tid = threadIdx.x;
  const int g = blockIdx.x & (NG - 1);   // group
  const int s = blockIdx.x >> 4;         // unit slice
  const int isF32 = g_isF32;             // wave-uniform (probe ran first)

  if (tid == 0) abortF = 0;

  auto ldf = [&](const void* p, int idx) -> float {
    return isF32 ? ((const float*)p)[idx] : bf2f(((const u16*)p)[idx]);
  };

  // ---- one-time: load transposed weight slices into LDS (as bf16) ----
  for (int i = tid; i < 64 * E_SZ; i += 256) {
    int k = i >> 6, n = i & 63;
    int col = ((n >> 4) << 8) + (s << 4) + (n & 15);
    w0t[n * EPAD + k] = f2bf(ldf(W0, k * 1024 + col));
  }
  for (int i = tid; i < 64 * U_SZ; i += 256) {
    int k = i >> 6, n = i & 63;
    int col = ((n >> 4) << 8) + (s << 4) + (n & 15);
    r0t[n * HS + k] = f2bf(ldf(R0, k * 1024 + col));
    w1t[n * HS + k] = f2bf(ldf(W1, k * 1024 + col));
    r1t[n * HS + k] = f2bf(ldf(R1, k * 1024 + col));
  }
  if (tid < 64) {
    int col = ((tid >> 4) << 8) + (s << 4) + (tid & 15);
    ldsB0[tid] = ldf(b0, col);
    ldsB1[tid] = ldf(b1, col);
  }
  for (int i = tid; i < MB * U_SZ; i += 256) {
    int m = i >> 8, k = i & 255;
    ldsH0[m * HS + k] = 0;
    ldsH1[m * HS + k] = 0;
  }

  const int lane = tid & 63;
  const int wv = tid >> 6;       // wave id == gate q (i,f,g,o)
  const int ml = lane & 15;
  const int quad = lane >> 4;
  const int um = tid >> 4;       // update phase: batch row
  const int un = tid & 15;       // update phase: unit within slice

  float c0 = 0.f, c1 = 0.f;
  const int tokBase = (g * MB + um) * T_STEPS;

  // prefetch x_0 into registers
  float4 xfA, xfB; uint4 xbf;
  {
    int tok = tokens[tokBase + 0];
    if (isF32) {
      const float* row = (const float*)emb + (u64)tok * E_SZ + (un << 3);
      xfA = *(const float4*)row; xfB = *(const float4*)(row + 4);
    } else {
      xbf = *(const uint4*)((const u16*)emb + (u64)tok * E_SZ + (un << 3));
    }
  }
  __syncthreads();

  for (int t = 0; t < T_STEPS; t++) {
    // A: commit prefetched x_t to LDS (bf16)
    {
      uint4 pk;
      if (isF32) {
        pk.x = (u32)f2bf(xfA.x) | ((u32)f2bf(xfA.y) << 16);
        pk.y = (u32)f2bf(xfA.z) | ((u32)f2bf(xfA.w) << 16);
        pk.z = (u32)f2bf(xfB.x) | ((u32)f2bf(xfB.y) << 16);
        pk.w = (u32)f2bf(xfB.z) | ((u32)f2bf(xfB.w) << 16);
      } else pk = xbf;
      *(uint4*)(ldsX + um * EPAD + (un << 3)) = pk;
    }
    __syncthreads();

    // B: z0 = b0 + x@W0 + h0_{t-1}@R0 ; gates0
    {
      float bias = ldsB0[(wv << 4) + ml];
      f32x4 acc = {bias, bias, bias, bias};
      const u16* ar = ldsX + ml * EPAD + (quad << 3);
      const u16* br = w0t + ((wv << 4) + ml) * EPAD + (quad << 3);
#pragma unroll
      for (int kc = 0; kc < 4; kc++) {
        bf16x8 av = *(const bf16x8*)(ar + kc * 32);
        bf16x8 bv = *(const bf16x8*)(br + kc * 32);
        acc = __builtin_amdgcn_mfma_f32_16x16x32_bf16(av, bv, acc, 0, 0, 0);
      }
      const u16* ar2 = ldsH0 + ml * HS + (quad << 3);
      const u16* br2 = r0t + ((wv << 4) + ml) * HS + (quad << 3);
#pragma unroll
      for (int kc = 0; kc < 8; kc++) {
        bf16x8 av = *(const bf16x8*)(ar2 + kc * 32);
        bf16x8 bv = *(const bf16x8*)(br2 + kc * 32);
        acc = __builtin_amdgcn_mfma_f32_16x16x32_bf16(av, bv, acc, 0, 0, 0);
      }
#pragma unroll
      for (int r = 0; r < 4; r++) {   // C/D: col=lane&15, row=quad*4+r
        float v = acc[r];
        float gv = (wv == 2) ? tanhf(v) : sigmoidf_(v);
        ldsG[((wv << 4) + (quad << 2) + r) * 17 + ml] = gv;
      }
    }
    __syncthreads();

    // cell update layer 0 -> stg
    {
      float iv = ldsG[um * 17 + un];
      float fv = ldsG[(16 + um) * 17 + un];
      float gv = ldsG[(32 + um) * 17 + un];
      float ov = ldsG[(48 + um) * 17 + un];
      c0 = fv * c0 + iv * gv;
      stg[(um << 4) + un] = f2bf(ov * tanhf(c0));
    }
    __syncthreads();

    // C: post h0_t
    postSlice(g_exch0, g_flags0, t, g, s, tid, stg);

    // issue x_{t+1} prefetch (in flight across waits below)
    if (t + 1 < T_STEPS) {
      int tok = tokens[tokBase + t + 1];
      if (isF32) {
        const float* row = (const float*)emb + (u64)tok * E_SZ + (un << 3);
        xfA = *(const float4*)row; xfB = *(const float4*)(row + 4);
      } else {
        xbf = *(const uint4*)((const u16*)emb + (u64)tok * E_SZ + (un << 3));
      }
    }

    // D: h1_{t-1} (posted last iter, usually ready) + R1 partial — hides h0 wait
    if (t > 0) {
      waitFlags(g_flags1, g, t, tid, &abortF);
      readback(g_exch1, t - 1, g, tid, ldsH1);
    }
    float bias1 = ldsB1[(wv << 4) + ml];
    f32x4 acc1 = {bias1, bias1, bias1, bias1};
    {
      const u16* ar2 = ldsH1 + ml * HS + (quad << 3);
      const u16* br2 = r1t + ((wv << 4) + ml) * HS + (quad << 3);
#pragma unroll
      for (int kc = 0; kc < 8; kc++) {
        bf16x8 av = *(const bf16x8*)(ar2 + kc * 32);
        bf16x8 bv = *(const bf16x8*)(br2 + kc * 32);
        acc1 = __builtin_amdgcn_mfma_f32_16x16x32_bf16(av, bv, acc1, 0, 0, 0);
      }
    }

    // E: rendezvous on h0_t
    waitFlags(g_flags0, g, t + 1, tid, &abortF);
    readback(g_exch0, t, g, tid, ldsH0);

    // F: acc1 += h0_t@W1 ; gates1
    {
      const u16* ar = ldsH0 + ml * HS + (quad << 3);
      const u16* br = w1t + ((wv << 4) + ml) * HS + (quad << 3);
#pragma unroll
      for (int kc = 0; kc < 8; kc++) {
        bf16x8 av = *(const bf16x8*)(ar + kc * 32);
        bf16x8 bv = *(const bf16x8*)(br + kc * 32);
        acc1 = __builtin_amdgcn_mfma_f32_16x16x32_bf16(av, bv, acc1, 0, 0, 0);
      }
#pragma unroll
      for (int r = 0; r < 4; r++) {
        float v = acc1[r];
        float gv = (wv == 2) ? tanhf(v) : sigmoidf_(v);
        ldsG[((wv << 4) + (quad << 2) + r) * 17 + ml] = gv;
      }
    }
    __syncthreads();

    // cell update layer 1 -> stg
    {
      float iv = ldsG[um * 17 + un];
      float fv = ldsG[(16 + um) * 17 + un];
      float gv = ldsG[(32 + um) * 17 + un];
      float ov = ldsG[(48 + um) * 17 + un];
      c1 = fv * c1 + iv * gv;
      stg[(um << 4) + un] = f2bf(ov * tanhf(c1));
    }
    __syncthreads();

    // G: post h1_t (wait deferred to next iter's phase D)
    postSlice(g_exch1, g_flags1, t, g, s, tid, stg);
  }

  // ---- epilogue: logits = h1_final @ Wout + bout; sigmoid ----
  if (s == 0) {
    waitFlags(g_flags1, g, T_STEPS, tid, &abortF);
    readback(g_exch1, T_STEPS - 1, g, tid, ldsH1);
    float* woutf = ldsG;          // 256 floats
    float* red = ldsG + 272;      // 16x17 partials
    woutf[tid] = ldf(Wout, tid);
    __syncthreads();
    float p = 0.f;
#pragma unroll
    for (int j = 0; j < 16; j++)
      p += bf2f(ldsH1[um * HS + (un << 4) + j]) * woutf[(un << 4) + j];
    red[um * 17 + un] = p;
    __syncthreads();
    if (tid < 16) {
      float sum = ldf(bout, 0);
#pragma unroll
      for (int j = 0; j < 16; j++) sum += red[tid * 17 + j];
      float val = sigmoidf_(sum);
      if (isF32) ((float*)outv)[g * MB + tid] = val;
      else       ((u16*)outv)[g * MB + tid] = f2bf(val);
    }
  }
}

extern "C" void kernel_launch(void* const* d_in, const int* in_sizes, int n_in,
                              void* d_out, int out_size, void* d_ws, size_t ws_size,
                              hipStream_t stream) {
  const int* tokens = (const int*)d_in[0];
  const void* emb  = d_in[1];
  const void* W0   = d_in[2];
  const void* R0   = d_in[3];
  const void* b0   = d_in[4];
  const void* W1   = d_in[5];
  const void* R1   = d_in[6];
  const void* b1   = d_in[7];
  const void* Wout = d_in[8];
  const void* bout = d_in[9];

  hipFuncSetAttribute((const void*)lstm_fused,
                      hipFuncAttributeMaxDynamicSharedMemorySize, SMEM_TOTAL);

  // probe: detects f32-vs-bf16 storage, zeroes sync flags (stream-ordered)
  dtype_probe<<<dim3(1), dim3(256), 0, stream>>>(W0);

  // grid = 256 wgs, 142 KiB LDS each -> exactly 1 wg/CU on 256 CUs: co-resident.
  lstm_fused<<<dim3(256), dim3(256), SMEM_TOTAL, stream>>>(
      tokens, emb, W0, R0, b0, W1, R1, b1, Wout, bout, d_out);
}